// Round 9
// baseline (625.803 us; speedup 1.0000x reference)
//
#include <hip/hip_runtime.h>
#include <hip/hip_bf16.h>
#include <hip/hip_fp16.h>

constexpr int N_ = 100000;
constexpr int E_ = 1600000;
constexpr int G_ = 1000;
constexpr int D_ = 128;
constexpr int C_ = 100;
constexpr int K_ = 2;
constexpr int L_ = 3;
constexpr int NSB = (N_ + 255) / 256;   // scan blocks = 391

// ---------------- init ----------------
__global__ void init_ws(int* __restrict__ deg, int* __restrict__ cursor) {
    int i = blockIdx.x * 256 + threadIdx.x;
    if (i < N_) { deg[i] = 1; cursor[i] = 0; }     // self-loop counted
}

__global__ void count_deg(const int* __restrict__ dst, int* __restrict__ deg) {
    int e = blockIdx.x * 256 + threadIdx.x;
    if (e < E_) atomicAdd(&deg[dst[e]], 1);
}

__global__ void compute_disq(const int* __restrict__ deg, float* __restrict__ dis) {
    int i = blockIdx.x * 256 + threadIdx.x;
    if (i < N_) dis[i] = 1.0f / sqrtf((float)deg[i]);   // deg >= 1 always
}

// ---------------- CSR build (hierarchical scan) ----------------
__global__ void scan_block_sums(const int* __restrict__ deg, int* __restrict__ bsums) {
    __shared__ int sh[256];
    int i = blockIdx.x * 256 + threadIdx.x;
    int v = (i < N_) ? (deg[i] - 1) : 0;   // counts exclude self-loop
    sh[threadIdx.x] = v;
    __syncthreads();
    for (int off = 128; off > 0; off >>= 1) {
        if (threadIdx.x < off) sh[threadIdx.x] += sh[threadIdx.x + off];
        __syncthreads();
    }
    if (threadIdx.x == 0) bsums[blockIdx.x] = sh[0];
}

__global__ void scan_offsets(int* __restrict__ bsums, int nb) {
    __shared__ int a[512], b[512];
    int t = threadIdx.x;
    int v = (t < nb) ? bsums[t] : 0;
    a[t] = v;
    __syncthreads();
    int* src = a; int* dst = b;
    for (int off = 1; off < 512; off <<= 1) {
        int x = src[t] + ((t >= off) ? src[t - off] : 0);
        dst[t] = x;
        __syncthreads();
        int* tmp = src; src = dst; dst = tmp;
    }
    if (t < nb) bsums[t] = src[t] - v;     // exclusive
}

__global__ void scan_write(const int* __restrict__ deg, const int* __restrict__ boffs,
                           int* __restrict__ rowp) {
    __shared__ int a[256], b[256];
    int t = threadIdx.x;
    int i = blockIdx.x * 256 + t;
    int v = (i < N_) ? (deg[i] - 1) : 0;
    a[t] = v;
    __syncthreads();
    int* src = a; int* dst = b;
    for (int off = 1; off < 256; off <<= 1) {
        int x = src[t] + ((t >= off) ? src[t - off] : 0);
        dst[t] = x;
        __syncthreads();
        int* tmp = src; src = dst; dst = tmp;
    }
    if (i < N_) rowp[i] = boffs[blockIdx.x] + src[t] - v;
    if (i == 0) rowp[N_] = E_;
}

__global__ void fill_csr(const int* __restrict__ srcv, const int* __restrict__ dstv,
                         const int* __restrict__ rowp, int* __restrict__ cursor,
                         int* __restrict__ csr) {
    int e = blockIdx.x * 256 + threadIdx.x;
    if (e >= E_) return;
    int d = dstv[e];
    int pos = atomicAdd(&cursor[d], 1);
    csr[rowp[d] + pos] = srcv[e];
}

// ---------------- embedding: h0 = x @ W_embed^T ----------------
__global__ __launch_bounds__(128) void embed_kernel(
    const float* __restrict__ x, const float* __restrict__ Wemb,
    float* __restrict__ h) {
    __shared__ float4 xs[64 * 4];
    int t = threadIdx.x;                      // output dim d (0..127)
    float w[16];
#pragma unroll
    for (int f = 0; f < 16; ++f) w[f] = Wemb[t * 16 + f];
    int n0 = blockIdx.x * 64;
    const float4* x4 = (const float4*)x;
    for (int idx = t; idx < 64 * 4; idx += 128) {
        int gi = n0 * 4 + idx;
        xs[idx] = (gi < N_ * 4) ? x4[gi] : make_float4(0.f, 0.f, 0.f, 0.f);
    }
    __syncthreads();
    int lim = min(64, N_ - n0);
    for (int j = 0; j < lim; ++j) {
        float4 x0 = xs[j * 4 + 0], x1 = xs[j * 4 + 1];
        float4 x2 = xs[j * 4 + 2], x3 = xs[j * 4 + 3];
        float acc = x0.x * w[0] + x0.y * w[1] + x0.z * w[2] + x0.w * w[3]
                  + x1.x * w[4] + x1.y * w[5] + x1.z * w[6] + x1.w * w[7]
                  + x2.x * w[8] + x2.y * w[9] + x2.z * w[10] + x2.w * w[11]
                  + x3.x * w[12] + x3.y * w[13] + x3.z * w[14] + x3.w * w[15];
        h[(size_t)(n0 + j) * 128 + t] = acc;
    }
}

// ---------------- big GEMM: 128x128 tile, BK=32, 8x8 per thread ----------
// Register-prefetch double buffering: next K-tile loads issue before compute,
// LDS write happens after the read barrier. Single 33KB LDS buffer kept.
// OUT16=1: write fp16 packed, scaled by dis[n]  (conv message matrix)
// OUT16=0: write fp32, no scale                 (centroid dots)
template<int OUT16>
__global__ __launch_bounds__(256) void big_gemm(
    const float* __restrict__ A, const float* __restrict__ W,
    void* __restrict__ outp, int ncols, const float* __restrict__ dis) {
    __shared__ float AshT[32][132];   // [kk][row], stride 132 (16B-aligned)
    __shared__ float WshT[32][132];   // [kk][col]
    int t = threadIdx.x;
    int tx = t & 15;                  // col octet: cols 8tx..8tx+7
    int ty = t >> 4;                  // row octet: rows 8ty..8ty+7 (0..15)
    int row0 = blockIdx.x * 128;
    int slot = t & 7;                 // float4 slot within the 32-k slice
    int rrow = t >> 3;                // 0..31 -> rows rrow + 32j

    float4 ra[4], rw[4];

    auto LOAD = [&](int kb) {
#pragma unroll
        for (int j = 0; j < 4; ++j) {
            int r = rrow + j * 32;
            int gr = row0 + r;
            ra[j] = (gr < N_) ? *(const float4*)&A[(size_t)gr * 128 + kb + (slot << 2)]
                              : make_float4(0.f, 0.f, 0.f, 0.f);
            rw[j] = (r < ncols) ? *(const float4*)&W[r * 128 + kb + (slot << 2)]
                                : make_float4(0.f, 0.f, 0.f, 0.f);
        }
    };
    auto STORE = [&]() {
        int q = slot << 2;
#pragma unroll
        for (int j = 0; j < 4; ++j) {
            int r = rrow + j * 32;
            AshT[q + 0][r] = ra[j].x; AshT[q + 1][r] = ra[j].y;
            AshT[q + 2][r] = ra[j].z; AshT[q + 3][r] = ra[j].w;
            WshT[q + 0][r] = rw[j].x; WshT[q + 1][r] = rw[j].y;
            WshT[q + 2][r] = rw[j].z; WshT[q + 3][r] = rw[j].w;
        }
    };

    float acc[8][8];
#pragma unroll
    for (int r = 0; r < 8; ++r)
#pragma unroll
        for (int c = 0; c < 8; ++c) acc[r][c] = 0.f;

    LOAD(0);
    STORE();
    for (int kb = 0; kb < 128; kb += 32) {
        __syncthreads();                 // LDS tile ready
        if (kb < 96) LOAD(kb + 32);      // prefetch next tile (overlaps compute)
#pragma unroll 2
        for (int kk = 0; kk < 32; ++kk) {
            float4 a0 = *(float4*)&AshT[kk][ty << 3];
            float4 a1 = *(float4*)&AshT[kk][(ty << 3) + 4];
            float4 w0 = *(float4*)&WshT[kk][tx << 3];
            float4 w1 = *(float4*)&WshT[kk][(tx << 3) + 4];
            float av[8] = {a0.x, a0.y, a0.z, a0.w, a1.x, a1.y, a1.z, a1.w};
            float wv[8] = {w0.x, w0.y, w0.z, w0.w, w1.x, w1.y, w1.z, w1.w};
#pragma unroll
            for (int r = 0; r < 8; ++r)
#pragma unroll
                for (int c = 0; c < 8; ++c)
                    acc[r][c] += av[r] * wv[c];
        }
        __syncthreads();                 // all reads done
        if (kb < 96) STORE();            // write prefetched tile
    }

    if (OUT16) {
        uint4* m4 = (uint4*)outp;
#pragma unroll
        for (int r = 0; r < 8; ++r) {
            int gr = row0 + (ty << 3) + r;
            if (gr < N_) {
                float s = dis[gr];
                __half2 p0 = __float22half2_rn(make_float2(acc[r][0] * s, acc[r][1] * s));
                __half2 p1 = __float22half2_rn(make_float2(acc[r][2] * s, acc[r][3] * s));
                __half2 p2 = __float22half2_rn(make_float2(acc[r][4] * s, acc[r][5] * s));
                __half2 p3 = __float22half2_rn(make_float2(acc[r][6] * s, acc[r][7] * s));
                uint4 u;
                u.x = *(unsigned int*)&p0; u.y = *(unsigned int*)&p1;
                u.z = *(unsigned int*)&p2; u.w = *(unsigned int*)&p3;
                m4[(size_t)gr * 16 + tx] = u;
            }
        }
    } else {
        float* o = (float*)outp;
#pragma unroll
        for (int r = 0; r < 8; ++r) {
            int gr = row0 + (ty << 3) + r;
            if (gr < N_) {
                *(float4*)&o[(size_t)gr * 128 + (tx << 3)] =
                    make_float4(acc[r][0], acc[r][1], acc[r][2], acc[r][3]);
                *(float4*)&o[(size_t)gr * 128 + (tx << 3) + 4] =
                    make_float4(acc[r][4], acc[r][5], acc[r][6], acc[r][7]);
            }
        }
    }
}

__device__ inline float4 h4f4(uint2 u) {
    float2 fa = __half22float2(*(__half2*)&u.x);
    float2 fb = __half22float2(*(__half2*)&u.y);
    return make_float4(fa.x, fa.y, fb.x, fb.y);
}

// ---------------- GCN aggregate: h[i] = relu(di * sum_{s in nbr+self} mh[s])
// mh fp16 rows (256B). 32 lanes per node, 8B/lane gathers, shfl-broadcast idx.
__global__ __launch_bounds__(256) void aggregate(
    const ushort* __restrict__ mh, float* __restrict__ hout,
    const int* __restrict__ rowp, const int* __restrict__ csr,
    const float* __restrict__ dis, float* __restrict__ x2out) {
    int t = threadIdx.x;
    int lane = t & 63;
    int l32 = lane & 31;
    int hbase = lane & 32;                       // 0 | 32
    int node = blockIdx.x * 8 + ((t >> 6) << 1) + (hbase >> 5);   // N_ % 8 == 0
    const uint2* m2 = (const uint2*)mh;

    float4 acc0 = h4f4(m2[(size_t)node * 32 + l32]);   // self-loop term
    float4 acc1 = make_float4(0.f, 0.f, 0.f, 0.f);
    int beg = rowp[node], end = rowp[node + 1];
    for (int base = beg; base < end; base += 32) {
        int cnt = end - base; if (cnt > 32) cnt = 32;
        int myidx = (l32 < cnt) ? csr[base + l32] : 0;
        int j = 0;
        for (; j + 8 <= cnt; j += 8) {
            int s0 = __shfl(myidx, hbase + j);
            int s1 = __shfl(myidx, hbase + j + 1);
            int s2 = __shfl(myidx, hbase + j + 2);
            int s3 = __shfl(myidx, hbase + j + 3);
            int s4 = __shfl(myidx, hbase + j + 4);
            int s5 = __shfl(myidx, hbase + j + 5);
            int s6 = __shfl(myidx, hbase + j + 6);
            int s7 = __shfl(myidx, hbase + j + 7);
            uint2 u0 = m2[(size_t)s0 * 32 + l32];
            uint2 u1 = m2[(size_t)s1 * 32 + l32];
            uint2 u2 = m2[(size_t)s2 * 32 + l32];
            uint2 u3 = m2[(size_t)s3 * 32 + l32];
            uint2 u4 = m2[(size_t)s4 * 32 + l32];
            uint2 u5 = m2[(size_t)s5 * 32 + l32];
            uint2 u6 = m2[(size_t)s6 * 32 + l32];
            uint2 u7 = m2[(size_t)s7 * 32 + l32];
            float4 v0 = h4f4(u0), v1 = h4f4(u1), v2 = h4f4(u2), v3 = h4f4(u3);
            float4 v4 = h4f4(u4), v5 = h4f4(u5), v6 = h4f4(u6), v7 = h4f4(u7);
            acc0.x += (v0.x + v1.x) + (v2.x + v3.x);
            acc0.y += (v0.y + v1.y) + (v2.y + v3.y);
            acc0.z += (v0.z + v1.z) + (v2.z + v3.z);
            acc0.w += (v0.w + v1.w) + (v2.w + v3.w);
            acc1.x += (v4.x + v5.x) + (v6.x + v7.x);
            acc1.y += (v4.y + v5.y) + (v6.y + v7.y);
            acc1.z += (v4.z + v5.z) + (v6.z + v7.z);
            acc1.w += (v4.w + v5.w) + (v6.w + v7.w);
        }
        for (; j + 4 <= cnt; j += 4) {
            int s0 = __shfl(myidx, hbase + j);
            int s1 = __shfl(myidx, hbase + j + 1);
            int s2 = __shfl(myidx, hbase + j + 2);
            int s3 = __shfl(myidx, hbase + j + 3);
            uint2 u0 = m2[(size_t)s0 * 32 + l32];
            uint2 u1 = m2[(size_t)s1 * 32 + l32];
            uint2 u2 = m2[(size_t)s2 * 32 + l32];
            uint2 u3 = m2[(size_t)s3 * 32 + l32];
            float4 v0 = h4f4(u0), v1 = h4f4(u1), v2 = h4f4(u2), v3 = h4f4(u3);
            acc0.x += (v0.x + v1.x) + (v2.x + v3.x);
            acc0.y += (v0.y + v1.y) + (v2.y + v3.y);
            acc0.z += (v0.z + v1.z) + (v2.z + v3.z);
            acc0.w += (v0.w + v1.w) + (v2.w + v3.w);
        }
        for (; j < cnt; ++j) {
            int s = __shfl(myidx, hbase + j);
            float4 v = h4f4(m2[(size_t)s * 32 + l32]);
            acc1.x += v.x; acc1.y += v.y; acc1.z += v.z; acc1.w += v.w;
        }
    }
    float di = dis[node];
    float4 hv;
    hv.x = fmaxf(di * (acc0.x + acc1.x), 0.f);
    hv.y = fmaxf(di * (acc0.y + acc1.y), 0.f);
    hv.z = fmaxf(di * (acc0.z + acc1.z), 0.f);
    hv.w = fmaxf(di * (acc0.w + acc1.w), 0.f);
    ((float4*)hout)[(size_t)node * 32 + l32] = hv;
    if (x2out) {                                  // row norm, free in registers
        float p = hv.x * hv.x + hv.y * hv.y + hv.z * hv.z + hv.w * hv.w;
        p += __shfl_xor(p, 1);
        p += __shfl_xor(p, 2);
        p += __shfl_xor(p, 4);
        p += __shfl_xor(p, 8);
        p += __shfl_xor(p, 16);
        if (l32 == 0) x2out[node] = p;
    }
}

// ---------------- centroid norms ----------------
__global__ void c2_kernel(const float* __restrict__ cent, float* __restrict__ c2) {
    int c = blockIdx.x;
    int t = threadIdx.x;    // 64
    float v0 = cent[c * 128 + t];
    float v1 = cent[c * 128 + 64 + t];
    float p = v0 * v0 + v1 * v1;
    for (int off = 32; off > 0; off >>= 1) p += __shfl_down(p, off);
    if (t == 0) c2[c] = p;
}

// ---------------- per-graph mean-pool of distances (batch is sorted) -------
__global__ __launch_bounds__(128) void pool_graph(
    const float* __restrict__ dots, const float* __restrict__ x2,
    const float* __restrict__ c2, const int* __restrict__ batch,
    float* __restrict__ pooled) {
    int g = blockIdx.x;
    int t = threadIdx.x;
    int lo = 0, hi = N_;
    while (lo < hi) { int mid = (lo + hi) >> 1; if (batch[mid] < g) lo = mid + 1; else hi = mid; }
    int s = lo;
    hi = N_;
    while (lo < hi) { int mid = (lo + hi) >> 1; if (batch[mid] < g + 1) lo = mid + 1; else hi = mid; }
    int e = lo;
    if (t >= C_) return;
    float cv = c2[t];
    float a0 = 0.f, a1 = 0.f, a2 = 0.f, a3 = 0.f;
    int n = s;
    for (; n + 4 <= e; n += 4) {
        float d0 = dots[(size_t)(n    ) * 128 + t];
        float d1 = dots[(size_t)(n + 1) * 128 + t];
        float d2 = dots[(size_t)(n + 2) * 128 + t];
        float d3 = dots[(size_t)(n + 3) * 128 + t];
        float x0 = x2[n], x1 = x2[n + 1], x2v = x2[n + 2], x3 = x2[n + 3];
        a0 += sqrtf(fmaxf(x0  + cv - 2.f * d0, 0.f) + 1e-12f);
        a1 += sqrtf(fmaxf(x1  + cv - 2.f * d1, 0.f) + 1e-12f);
        a2 += sqrtf(fmaxf(x2v + cv - 2.f * d2, 0.f) + 1e-12f);
        a3 += sqrtf(fmaxf(x3  + cv - 2.f * d3, 0.f) + 1e-12f);
    }
    for (; n < e; ++n) {
        float d = dots[(size_t)n * 128 + t];
        a0 += sqrtf(fmaxf(x2[n] + cv - 2.f * d, 0.f) + 1e-12f);
    }
    float inv = 1.0f / fmaxf((float)(e - s), 1.0f);
    pooled[g * C_ + t] = (a0 + a1 + a2 + a3) * inv;
}

// ---------------- final: out = pooled @ W_out^T + b_out ----------------
__global__ void final_out(const float* __restrict__ pooled,
                          const float* __restrict__ W_out, const float* __restrict__ b_out,
                          float* __restrict__ out) {
    int i = blockIdx.x * 256 + threadIdx.x;
    if (i >= G_ * K_) return;
    int g = i >> 1, k = i & 1;
    float acc = 0.f;
    for (int c = 0; c < C_; ++c) acc += pooled[g * C_ + c] * W_out[k * C_ + c];
    out[i] = acc + b_out[k];
}

extern "C" void kernel_launch(void* const* d_in, const int* in_sizes, int n_in,
                              void* d_out, int out_size, void* d_ws, size_t ws_size,
                              hipStream_t stream) {
    const float* x       = (const float*)d_in[0];
    const int*   eidx    = (const int*)d_in[1];    // [2][E]: src then dst
    const int*   batch   = (const int*)d_in[2];
    const float* W_embed = (const float*)d_in[3];
    const float* W_convs = (const float*)d_in[4];
    const float* cent    = (const float*)d_in[5];
    const float* W_out   = (const float*)d_in[6];
    const float* b_out   = (const float*)d_in[7];
    float* out = (float*)d_out;

    char* p = (char*)d_ws;
    float*  h    = (float*)p;  p += (size_t)N_ * D_ * 4;   // fp32 node features
    float*  dots = (float*)p;  p += (size_t)N_ * D_ * 4;   // fp32 h@cent^T
    ushort* mh   = (ushort*)p; p += (size_t)N_ * D_ * 2;   // fp16 messages
    int*   deg  = (int*)p;   p += (size_t)N_ * 4;
    float* dis  = (float*)p; p += (size_t)N_ * 4;
    int*   rowp = (int*)p;   p += (size_t)(N_ + 2) * 4;
    int*   curs = (int*)p;   p += (size_t)N_ * 4;
    int*   csr  = (int*)p;   p += (size_t)E_ * 4;
    int*   bsum = (int*)p;   p += (size_t)512 * 4;
    float* c2   = (float*)p; p += (size_t)128 * 4;
    float* x2   = (float*)p; p += (size_t)N_ * 4;
    float* pool = (float*)p; p += (size_t)G_ * C_ * 4;

    const int* esrc = eidx;
    const int* edst = eidx + E_;

    init_ws<<<(N_ + 255) / 256, 256, 0, stream>>>(deg, curs);
    count_deg<<<(E_ + 255) / 256, 256, 0, stream>>>(edst, deg);
    compute_disq<<<(N_ + 255) / 256, 256, 0, stream>>>(deg, dis);
    scan_block_sums<<<NSB, 256, 0, stream>>>(deg, bsum);
    scan_offsets<<<1, 512, 0, stream>>>(bsum, NSB);
    scan_write<<<NSB, 256, 0, stream>>>(deg, bsum, rowp);
    fill_csr<<<(E_ + 255) / 256, 256, 0, stream>>>(esrc, edst, rowp, curs, csr);

    // h0 = x @ W_embed^T
    embed_kernel<<<(N_ + 63) / 64, 128, 0, stream>>>(x, W_embed, h);

    int ngb = (N_ + 127) / 128;   // 782
    for (int l = 0; l < L_; ++l) {
        big_gemm<1><<<ngb, 256, 0, stream>>>(h, W_convs + (size_t)l * D_ * D_,
                                             (void*)mh, 128, dis);
        aggregate<<<N_ / 8, 256, 0, stream>>>(mh, h, rowp, csr, dis,
                                              (l == L_ - 1) ? x2 : nullptr);
    }

    // dots = h @ centroids^T (cols 100..127 zero-padded)
    big_gemm<0><<<ngb, 256, 0, stream>>>(h, cent, (void*)dots, 100, nullptr);
    c2_kernel<<<C_, 64, 0, stream>>>(cent, c2);
    pool_graph<<<G_, 128, 0, stream>>>(dots, x2, c2, batch, pool);
    final_out<<<(G_ * K_ + 255) / 256, 256, 0, stream>>>(pool, W_out, b_out, out);
}

// Round 10
// 582.741 us; speedup vs baseline: 1.0739x; 1.0739x over previous
//
#include <hip/hip_runtime.h>
#include <hip/hip_bf16.h>
#include <hip/hip_fp16.h>

constexpr int N_ = 100000;
constexpr int E_ = 1600000;
constexpr int G_ = 1000;
constexpr int D_ = 128;
constexpr int C_ = 100;
constexpr int K_ = 2;
constexpr int L_ = 3;
constexpr int NSB = (N_ + 255) / 256;   // scan blocks = 391
constexpr int NR_ = 8;                  // XCD dst-ranges
constexpr int RN_ = (N_ + NR_ - 1) / NR_;   // 12500 nodes per range
constexpr int EPB_ = 1280;              // edges per chunk
constexpr int NCH_ = (E_ + EPB_ - 1) / EPB_; // 1250 chunks

// ---------------- init ----------------
__global__ void init_ws(int* __restrict__ deg, int* __restrict__ cursor) {
    int i = blockIdx.x * 256 + threadIdx.x;
    if (i < N_) { deg[i] = 1; cursor[i] = 0; }     // self-loop counted
}

__global__ void count_deg(const int* __restrict__ dst, int* __restrict__ deg) {
    int e = blockIdx.x * 256 + threadIdx.x;
    if (e < E_) atomicAdd(&deg[dst[e]], 1);
}

__global__ void compute_disq(const int* __restrict__ deg, float* __restrict__ dis) {
    int i = blockIdx.x * 256 + threadIdx.x;
    if (i < N_) dis[i] = 1.0f / sqrtf((float)deg[i]);   // deg >= 1 always
}

// ---------------- CSR build (hierarchical scan) ----------------
__global__ void scan_block_sums(const int* __restrict__ deg, int* __restrict__ bsums) {
    __shared__ int sh[256];
    int i = blockIdx.x * 256 + threadIdx.x;
    int v = (i < N_) ? (deg[i] - 1) : 0;   // counts exclude self-loop
    sh[threadIdx.x] = v;
    __syncthreads();
    for (int off = 128; off > 0; off >>= 1) {
        if (threadIdx.x < off) sh[threadIdx.x] += sh[threadIdx.x + off];
        __syncthreads();
    }
    if (threadIdx.x == 0) bsums[blockIdx.x] = sh[0];
}

__global__ void scan_offsets(int* __restrict__ bsums, int nb) {
    __shared__ int a[512], b[512];
    int t = threadIdx.x;
    int v = (t < nb) ? bsums[t] : 0;
    a[t] = v;
    __syncthreads();
    int* src = a; int* dst = b;
    for (int off = 1; off < 512; off <<= 1) {
        int x = src[t] + ((t >= off) ? src[t - off] : 0);
        dst[t] = x;
        __syncthreads();
        int* tmp = src; src = dst; dst = tmp;
    }
    if (t < nb) bsums[t] = src[t] - v;     // exclusive
}

__global__ void scan_write(const int* __restrict__ deg, const int* __restrict__ boffs,
                           int* __restrict__ rowp) {
    __shared__ int a[256], b[256];
    int t = threadIdx.x;
    int i = blockIdx.x * 256 + t;
    int v = (i < N_) ? (deg[i] - 1) : 0;
    a[t] = v;
    __syncthreads();
    int* src = a; int* dst = b;
    for (int off = 1; off < 256; off <<= 1) {
        int x = src[t] + ((t >= off) ? src[t - off] : 0);
        dst[t] = x;
        __syncthreads();
        int* tmp = src; src = dst; dst = tmp;
    }
    if (i < N_) rowp[i] = boffs[blockIdx.x] + src[t] - v;
    if (i == 0) rowp[N_] = E_;
}

// XCD-partitioned CSR fill: block b handles dst range (b&7) on edge chunk
// (b>>3). Range r's cursor (50KB) and csr window (~800KB) are touched only
// by blocks that land on XCD r (blockIdx round-robin) -> writes stay in one
// L2, lines fill before eviction. Edge re-reads (8x) are L3-served.
__global__ __launch_bounds__(256) void fill_csr_xcd(
    const int* __restrict__ srcv, const int* __restrict__ dstv,
    const int* __restrict__ rowp, int* __restrict__ cursor,
    int* __restrict__ csr) {
    int r = blockIdx.x & 7;
    int chunk = blockIdx.x >> 3;
    int lo = r * RN_;
    int hi = lo + RN_;
    int ebeg = chunk * EPB_;
    int eend = ebeg + EPB_; if (eend > E_) eend = E_;
    for (int e = ebeg + threadIdx.x; e < eend; e += 256) {
        int d = dstv[e];
        if (d >= lo && d < hi) {
            int pos = atomicAdd(&cursor[d], 1);
            csr[rowp[d] + pos] = srcv[e];
        }
    }
}

// ---------------- embedding: h0 = x @ W_embed^T ----------------
__global__ __launch_bounds__(128) void embed_kernel(
    const float* __restrict__ x, const float* __restrict__ Wemb,
    float* __restrict__ h) {
    __shared__ float4 xs[64 * 4];
    int t = threadIdx.x;                      // output dim d (0..127)
    float w[16];
#pragma unroll
    for (int f = 0; f < 16; ++f) w[f] = Wemb[t * 16 + f];
    int n0 = blockIdx.x * 64;
    const float4* x4 = (const float4*)x;
    for (int idx = t; idx < 64 * 4; idx += 128) {
        int gi = n0 * 4 + idx;
        xs[idx] = (gi < N_ * 4) ? x4[gi] : make_float4(0.f, 0.f, 0.f, 0.f);
    }
    __syncthreads();
    int lim = min(64, N_ - n0);
    for (int j = 0; j < lim; ++j) {
        float4 x0 = xs[j * 4 + 0], x1 = xs[j * 4 + 1];
        float4 x2 = xs[j * 4 + 2], x3 = xs[j * 4 + 3];
        float acc = x0.x * w[0] + x0.y * w[1] + x0.z * w[2] + x0.w * w[3]
                  + x1.x * w[4] + x1.y * w[5] + x1.z * w[6] + x1.w * w[7]
                  + x2.x * w[8] + x2.y * w[9] + x2.z * w[10] + x2.w * w[11]
                  + x3.x * w[12] + x3.y * w[13] + x3.z * w[14] + x3.w * w[15];
        h[(size_t)(n0 + j) * 128 + t] = acc;
    }
}

// ---------------- big GEMM: 128x128 tile, BK=32, 8x8 per thread ----------
// out[n][c] = sum_k A[n][k] * W[c][k]
// OUT16=1: write fp16 packed, scaled by dis[n]  (conv message matrix)
// OUT16=0: write fp32, no scale                 (centroid dots)
template<int OUT16>
__global__ __launch_bounds__(256) void big_gemm(
    const float* __restrict__ A, const float* __restrict__ W,
    void* __restrict__ outp, int ncols, const float* __restrict__ dis) {
    __shared__ float AshT[32][132];   // [kk][row], stride 132 (16B-aligned)
    __shared__ float WshT[32][132];   // [kk][col]
    int t = threadIdx.x;
    int tx = t & 15;                  // col octet: cols 8tx..8tx+7
    int ty = t >> 4;                  // row octet: rows 8ty..8ty+7 (0..15)
    int row0 = blockIdx.x * 128;

    float acc[8][8];
#pragma unroll
    for (int r = 0; r < 8; ++r)
#pragma unroll
        for (int c = 0; c < 8; ++c) acc[r][c] = 0.f;

    for (int kb = 0; kb < 128; kb += 32) {
        __syncthreads();
        // stage A^T: 128 rows x 32 k; 8 lanes cover one row's 128B slice
        for (int idx = t; idx < 1024; idx += 256) {
            int slot = idx & 7, r = idx >> 3;
            int gr = row0 + r;
            float4 v = make_float4(0.f, 0.f, 0.f, 0.f);
            if (gr < N_) v = *(const float4*)&A[(size_t)gr * 128 + kb + (slot << 2)];
            int q = slot << 2;
            AshT[q + 0][r] = v.x; AshT[q + 1][r] = v.y;
            AshT[q + 2][r] = v.z; AshT[q + 3][r] = v.w;
        }
        // stage W^T likewise
        for (int idx = t; idx < 1024; idx += 256) {
            int slot = idx & 7, c = idx >> 3;
            float4 v = make_float4(0.f, 0.f, 0.f, 0.f);
            if (c < ncols) v = *(const float4*)&W[c * 128 + kb + (slot << 2)];
            int q = slot << 2;
            WshT[q + 0][c] = v.x; WshT[q + 1][c] = v.y;
            WshT[q + 2][c] = v.z; WshT[q + 3][c] = v.w;
        }
        __syncthreads();
#pragma unroll 2
        for (int kk = 0; kk < 32; ++kk) {
            float4 a0 = *(float4*)&AshT[kk][ty << 3];
            float4 a1 = *(float4*)&AshT[kk][(ty << 3) + 4];
            float4 w0 = *(float4*)&WshT[kk][tx << 3];
            float4 w1 = *(float4*)&WshT[kk][(tx << 3) + 4];
            float av[8] = {a0.x, a0.y, a0.z, a0.w, a1.x, a1.y, a1.z, a1.w};
            float wv[8] = {w0.x, w0.y, w0.z, w0.w, w1.x, w1.y, w1.z, w1.w};
#pragma unroll
            for (int r = 0; r < 8; ++r)
#pragma unroll
                for (int c = 0; c < 8; ++c)
                    acc[r][c] += av[r] * wv[c];
        }
    }

    if (OUT16) {
        uint4* m4 = (uint4*)outp;
#pragma unroll
        for (int r = 0; r < 8; ++r) {
            int gr = row0 + (ty << 3) + r;
            if (gr < N_) {
                float s = dis[gr];
                __half2 p0 = __float22half2_rn(make_float2(acc[r][0] * s, acc[r][1] * s));
                __half2 p1 = __float22half2_rn(make_float2(acc[r][2] * s, acc[r][3] * s));
                __half2 p2 = __float22half2_rn(make_float2(acc[r][4] * s, acc[r][5] * s));
                __half2 p3 = __float22half2_rn(make_float2(acc[r][6] * s, acc[r][7] * s));
                uint4 u;
                u.x = *(unsigned int*)&p0; u.y = *(unsigned int*)&p1;
                u.z = *(unsigned int*)&p2; u.w = *(unsigned int*)&p3;
                m4[(size_t)gr * 16 + tx] = u;
            }
        }
    } else {
        float* o = (float*)outp;
#pragma unroll
        for (int r = 0; r < 8; ++r) {
            int gr = row0 + (ty << 3) + r;
            if (gr < N_) {
                *(float4*)&o[(size_t)gr * 128 + (tx << 3)] =
                    make_float4(acc[r][0], acc[r][1], acc[r][2], acc[r][3]);
                *(float4*)&o[(size_t)gr * 128 + (tx << 3) + 4] =
                    make_float4(acc[r][4], acc[r][5], acc[r][6], acc[r][7]);
            }
        }
    }
}

__device__ inline float4 h4f4(uint2 u) {
    float2 fa = __half22float2(*(__half2*)&u.x);
    float2 fb = __half22float2(*(__half2*)&u.y);
    return make_float4(fa.x, fa.y, fb.x, fb.y);
}

// ---------------- GCN aggregate: h[i] = relu(di * sum_{s in nbr+self} mh[s])
// mh fp16 rows (256B). 32 lanes per node, 8B/lane gathers, shfl-broadcast idx.
__global__ __launch_bounds__(256) void aggregate(
    const ushort* __restrict__ mh, float* __restrict__ hout,
    const int* __restrict__ rowp, const int* __restrict__ csr,
    const float* __restrict__ dis, float* __restrict__ x2out) {
    int t = threadIdx.x;
    int lane = t & 63;
    int l32 = lane & 31;
    int hbase = lane & 32;                       // 0 | 32
    int node = blockIdx.x * 8 + ((t >> 6) << 1) + (hbase >> 5);   // N_ % 8 == 0
    const uint2* m2 = (const uint2*)mh;

    float4 acc0 = h4f4(m2[(size_t)node * 32 + l32]);   // self-loop term
    float4 acc1 = make_float4(0.f, 0.f, 0.f, 0.f);
    int beg = rowp[node], end = rowp[node + 1];
    for (int base = beg; base < end; base += 32) {
        int cnt = end - base; if (cnt > 32) cnt = 32;
        int myidx = (l32 < cnt) ? csr[base + l32] : 0;
        int j = 0;
        for (; j + 8 <= cnt; j += 8) {
            int s0 = __shfl(myidx, hbase + j);
            int s1 = __shfl(myidx, hbase + j + 1);
            int s2 = __shfl(myidx, hbase + j + 2);
            int s3 = __shfl(myidx, hbase + j + 3);
            int s4 = __shfl(myidx, hbase + j + 4);
            int s5 = __shfl(myidx, hbase + j + 5);
            int s6 = __shfl(myidx, hbase + j + 6);
            int s7 = __shfl(myidx, hbase + j + 7);
            uint2 u0 = m2[(size_t)s0 * 32 + l32];
            uint2 u1 = m2[(size_t)s1 * 32 + l32];
            uint2 u2 = m2[(size_t)s2 * 32 + l32];
            uint2 u3 = m2[(size_t)s3 * 32 + l32];
            uint2 u4 = m2[(size_t)s4 * 32 + l32];
            uint2 u5 = m2[(size_t)s5 * 32 + l32];
            uint2 u6 = m2[(size_t)s6 * 32 + l32];
            uint2 u7 = m2[(size_t)s7 * 32 + l32];
            float4 v0 = h4f4(u0), v1 = h4f4(u1), v2 = h4f4(u2), v3 = h4f4(u3);
            float4 v4 = h4f4(u4), v5 = h4f4(u5), v6 = h4f4(u6), v7 = h4f4(u7);
            acc0.x += (v0.x + v1.x) + (v2.x + v3.x);
            acc0.y += (v0.y + v1.y) + (v2.y + v3.y);
            acc0.z += (v0.z + v1.z) + (v2.z + v3.z);
            acc0.w += (v0.w + v1.w) + (v2.w + v3.w);
            acc1.x += (v4.x + v5.x) + (v6.x + v7.x);
            acc1.y += (v4.y + v5.y) + (v6.y + v7.y);
            acc1.z += (v4.z + v5.z) + (v6.z + v7.z);
            acc1.w += (v4.w + v5.w) + (v6.w + v7.w);
        }
        for (; j + 4 <= cnt; j += 4) {
            int s0 = __shfl(myidx, hbase + j);
            int s1 = __shfl(myidx, hbase + j + 1);
            int s2 = __shfl(myidx, hbase + j + 2);
            int s3 = __shfl(myidx, hbase + j + 3);
            uint2 u0 = m2[(size_t)s0 * 32 + l32];
            uint2 u1 = m2[(size_t)s1 * 32 + l32];
            uint2 u2 = m2[(size_t)s2 * 32 + l32];
            uint2 u3 = m2[(size_t)s3 * 32 + l32];
            float4 v0 = h4f4(u0), v1 = h4f4(u1), v2 = h4f4(u2), v3 = h4f4(u3);
            acc0.x += (v0.x + v1.x) + (v2.x + v3.x);
            acc0.y += (v0.y + v1.y) + (v2.y + v3.y);
            acc0.z += (v0.z + v1.z) + (v2.z + v3.z);
            acc0.w += (v0.w + v1.w) + (v2.w + v3.w);
        }
        for (; j < cnt; ++j) {
            int s = __shfl(myidx, hbase + j);
            float4 v = h4f4(m2[(size_t)s * 32 + l32]);
            acc1.x += v.x; acc1.y += v.y; acc1.z += v.z; acc1.w += v.w;
        }
    }
    float di = dis[node];
    float4 hv;
    hv.x = fmaxf(di * (acc0.x + acc1.x), 0.f);
    hv.y = fmaxf(di * (acc0.y + acc1.y), 0.f);
    hv.z = fmaxf(di * (acc0.z + acc1.z), 0.f);
    hv.w = fmaxf(di * (acc0.w + acc1.w), 0.f);
    ((float4*)hout)[(size_t)node * 32 + l32] = hv;
    if (x2out) {                                  // row norm, free in registers
        float p = hv.x * hv.x + hv.y * hv.y + hv.z * hv.z + hv.w * hv.w;
        p += __shfl_xor(p, 1);
        p += __shfl_xor(p, 2);
        p += __shfl_xor(p, 4);
        p += __shfl_xor(p, 8);
        p += __shfl_xor(p, 16);
        if (l32 == 0) x2out[node] = p;
    }
}

// ---------------- centroid norms ----------------
__global__ void c2_kernel(const float* __restrict__ cent, float* __restrict__ c2) {
    int c = blockIdx.x;
    int t = threadIdx.x;    // 64
    float v0 = cent[c * 128 + t];
    float v1 = cent[c * 128 + 64 + t];
    float p = v0 * v0 + v1 * v1;
    for (int off = 32; off > 0; off >>= 1) p += __shfl_down(p, off);
    if (t == 0) c2[c] = p;
}

// ---------------- per-graph mean-pool of distances (batch is sorted) -------
__global__ __launch_bounds__(128) void pool_graph(
    const float* __restrict__ dots, const float* __restrict__ x2,
    const float* __restrict__ c2, const int* __restrict__ batch,
    float* __restrict__ pooled) {
    int g = blockIdx.x;
    int t = threadIdx.x;
    int lo = 0, hi = N_;
    while (lo < hi) { int mid = (lo + hi) >> 1; if (batch[mid] < g) lo = mid + 1; else hi = mid; }
    int s = lo;
    hi = N_;
    while (lo < hi) { int mid = (lo + hi) >> 1; if (batch[mid] < g + 1) lo = mid + 1; else hi = mid; }
    int e = lo;
    if (t >= C_) return;
    float cv = c2[t];
    float a0 = 0.f, a1 = 0.f, a2 = 0.f, a3 = 0.f;
    int n = s;
    for (; n + 4 <= e; n += 4) {
        float d0 = dots[(size_t)(n    ) * 128 + t];
        float d1 = dots[(size_t)(n + 1) * 128 + t];
        float d2 = dots[(size_t)(n + 2) * 128 + t];
        float d3 = dots[(size_t)(n + 3) * 128 + t];
        float x0 = x2[n], x1 = x2[n + 1], x2v = x2[n + 2], x3 = x2[n + 3];
        a0 += sqrtf(fmaxf(x0  + cv - 2.f * d0, 0.f) + 1e-12f);
        a1 += sqrtf(fmaxf(x1  + cv - 2.f * d1, 0.f) + 1e-12f);
        a2 += sqrtf(fmaxf(x2v + cv - 2.f * d2, 0.f) + 1e-12f);
        a3 += sqrtf(fmaxf(x3  + cv - 2.f * d3, 0.f) + 1e-12f);
    }
    for (; n < e; ++n) {
        float d = dots[(size_t)n * 128 + t];
        a0 += sqrtf(fmaxf(x2[n] + cv - 2.f * d, 0.f) + 1e-12f);
    }
    float inv = 1.0f / fmaxf((float)(e - s), 1.0f);
    pooled[g * C_ + t] = (a0 + a1 + a2 + a3) * inv;
}

// ---------------- final: out = pooled @ W_out^T + b_out ----------------
__global__ void final_out(const float* __restrict__ pooled,
                          const float* __restrict__ W_out, const float* __restrict__ b_out,
                          float* __restrict__ out) {
    int i = blockIdx.x * 256 + threadIdx.x;
    if (i >= G_ * K_) return;
    int g = i >> 1, k = i & 1;
    float acc = 0.f;
    for (int c = 0; c < C_; ++c) acc += pooled[g * C_ + c] * W_out[k * C_ + c];
    out[i] = acc + b_out[k];
}

extern "C" void kernel_launch(void* const* d_in, const int* in_sizes, int n_in,
                              void* d_out, int out_size, void* d_ws, size_t ws_size,
                              hipStream_t stream) {
    const float* x       = (const float*)d_in[0];
    const int*   eidx    = (const int*)d_in[1];    // [2][E]: src then dst
    const int*   batch   = (const int*)d_in[2];
    const float* W_embed = (const float*)d_in[3];
    const float* W_convs = (const float*)d_in[4];
    const float* cent    = (const float*)d_in[5];
    const float* W_out   = (const float*)d_in[6];
    const float* b_out   = (const float*)d_in[7];
    float* out = (float*)d_out;

    char* p = (char*)d_ws;
    float*  h    = (float*)p;  p += (size_t)N_ * D_ * 4;   // fp32 node features
    float*  dots = (float*)p;  p += (size_t)N_ * D_ * 4;   // fp32 h@cent^T
    ushort* mh   = (ushort*)p; p += (size_t)N_ * D_ * 2;   // fp16 messages
    int*   deg  = (int*)p;   p += (size_t)N_ * 4;
    float* dis  = (float*)p; p += (size_t)N_ * 4;
    int*   rowp = (int*)p;   p += (size_t)(N_ + 2) * 4;
    int*   curs = (int*)p;   p += (size_t)N_ * 4;
    int*   csr  = (int*)p;   p += (size_t)E_ * 4;
    int*   bsum = (int*)p;   p += (size_t)512 * 4;
    float* c2   = (float*)p; p += (size_t)128 * 4;
    float* x2   = (float*)p; p += (size_t)N_ * 4;
    float* pool = (float*)p; p += (size_t)G_ * C_ * 4;

    const int* esrc = eidx;
    const int* edst = eidx + E_;

    init_ws<<<(N_ + 255) / 256, 256, 0, stream>>>(deg, curs);
    count_deg<<<(E_ + 255) / 256, 256, 0, stream>>>(edst, deg);
    compute_disq<<<(N_ + 255) / 256, 256, 0, stream>>>(deg, dis);
    scan_block_sums<<<NSB, 256, 0, stream>>>(deg, bsum);
    scan_offsets<<<1, 512, 0, stream>>>(bsum, NSB);
    scan_write<<<NSB, 256, 0, stream>>>(deg, bsum, rowp);
    fill_csr_xcd<<<NR_ * NCH_, 256, 0, stream>>>(esrc, edst, rowp, curs, csr);

    // h0 = x @ W_embed^T
    embed_kernel<<<(N_ + 63) / 64, 128, 0, stream>>>(x, W_embed, h);

    int ngb = (N_ + 127) / 128;   // 782
    for (int l = 0; l < L_; ++l) {
        big_gemm<1><<<ngb, 256, 0, stream>>>(h, W_convs + (size_t)l * D_ * D_,
                                             (void*)mh, 128, dis);
        aggregate<<<N_ / 8, 256, 0, stream>>>(mh, h, rowp, csr, dis,
                                              (l == L_ - 1) ? x2 : nullptr);
    }

    // dots = h @ centroids^T (cols 100..127 zero-padded)
    big_gemm<0><<<ngb, 256, 0, stream>>>(h, cent, (void*)dots, 100, nullptr);
    c2_kernel<<<C_, 64, 0, stream>>>(cent, c2);
    pool_graph<<<G_, 128, 0, stream>>>(dots, x2, c2, batch, pool);
    final_out<<<(G_ * K_ + 255) / 256, 256, 0, stream>>>(pool, W_out, b_out, out);
}

// Round 11
// 476.145 us; speedup vs baseline: 1.3143x; 1.2239x over previous
//
#include <hip/hip_runtime.h>
#include <hip/hip_bf16.h>
#include <hip/hip_fp16.h>

constexpr int N_ = 100000;
constexpr int E_ = 1600000;
constexpr int G_ = 1000;
constexpr int D_ = 128;
constexpr int C_ = 100;
constexpr int K_ = 2;
constexpr int L_ = 3;
constexpr int NSB = (N_ + 255) / 256;   // scan blocks = 391
constexpr int NR_ = 8;                  // XCD dst-ranges
constexpr int RN_ = (N_ + NR_ - 1) / NR_;   // 12500 nodes per range
constexpr int EPB_ = 1280;              // edges per chunk
constexpr int NCH_ = (E_ + EPB_ - 1) / EPB_; // 1250 chunks

using f16x8 = __attribute__((ext_vector_type(8))) _Float16;
using f16x4 = __attribute__((ext_vector_type(4))) _Float16;
using f32x4 = __attribute__((ext_vector_type(4))) float;

// ---------------- init ----------------
__global__ void init_ws(int* __restrict__ deg, int* __restrict__ cursor) {
    int i = blockIdx.x * 256 + threadIdx.x;
    if (i < N_) { deg[i] = 1; cursor[i] = 0; }     // self-loop counted
}

__global__ void count_deg(const int* __restrict__ dst, int* __restrict__ deg) {
    int e = blockIdx.x * 256 + threadIdx.x;
    if (e < E_) atomicAdd(&deg[dst[e]], 1);
}

__global__ void compute_disq(const int* __restrict__ deg, float* __restrict__ dis) {
    int i = blockIdx.x * 256 + threadIdx.x;
    if (i < N_) dis[i] = 1.0f / sqrtf((float)deg[i]);   // deg >= 1 always
}

// ---------------- CSR build (hierarchical scan) ----------------
__global__ void scan_block_sums(const int* __restrict__ deg, int* __restrict__ bsums) {
    __shared__ int sh[256];
    int i = blockIdx.x * 256 + threadIdx.x;
    int v = (i < N_) ? (deg[i] - 1) : 0;   // counts exclude self-loop
    sh[threadIdx.x] = v;
    __syncthreads();
    for (int off = 128; off > 0; off >>= 1) {
        if (threadIdx.x < off) sh[threadIdx.x] += sh[threadIdx.x + off];
        __syncthreads();
    }
    if (threadIdx.x == 0) bsums[blockIdx.x] = sh[0];
}

__global__ void scan_offsets(int* __restrict__ bsums, int nb) {
    __shared__ int a[512], b[512];
    int t = threadIdx.x;
    int v = (t < nb) ? bsums[t] : 0;
    a[t] = v;
    __syncthreads();
    int* src = a; int* dst = b;
    for (int off = 1; off < 512; off <<= 1) {
        int x = src[t] + ((t >= off) ? src[t - off] : 0);
        dst[t] = x;
        __syncthreads();
        int* tmp = src; src = dst; dst = tmp;
    }
    if (t < nb) bsums[t] = src[t] - v;     // exclusive
}

__global__ void scan_write(const int* __restrict__ deg, const int* __restrict__ boffs,
                           int* __restrict__ rowp) {
    __shared__ int a[256], b[256];
    int t = threadIdx.x;
    int i = blockIdx.x * 256 + t;
    int v = (i < N_) ? (deg[i] - 1) : 0;
    a[t] = v;
    __syncthreads();
    int* src = a; int* dst = b;
    for (int off = 1; off < 256; off <<= 1) {
        int x = src[t] + ((t >= off) ? src[t - off] : 0);
        dst[t] = x;
        __syncthreads();
        int* tmp = src; src = dst; dst = tmp;
    }
    if (i < N_) rowp[i] = boffs[blockIdx.x] + src[t] - v;
    if (i == 0) rowp[N_] = E_;
}

// XCD-partitioned CSR fill (round-10 win: write locality per XCD L2)
__global__ __launch_bounds__(256) void fill_csr_xcd(
    const int* __restrict__ srcv, const int* __restrict__ dstv,
    const int* __restrict__ rowp, int* __restrict__ cursor,
    int* __restrict__ csr) {
    int r = blockIdx.x & 7;
    int chunk = blockIdx.x >> 3;
    int lo = r * RN_;
    int hi = lo + RN_;
    int ebeg = chunk * EPB_;
    int eend = ebeg + EPB_; if (eend > E_) eend = E_;
    for (int e = ebeg + threadIdx.x; e < eend; e += 256) {
        int d = dstv[e];
        if (d >= lo && d < hi) {
            int pos = atomicAdd(&cursor[d], 1);
            csr[rowp[d] + pos] = srcv[e];
        }
    }
}

// ---------------- embedding: h0 = fp16( x @ W_embed^T ) ----------------
__global__ __launch_bounds__(128) void embed_kernel(
    const float* __restrict__ x, const float* __restrict__ Wemb,
    _Float16* __restrict__ h) {
    __shared__ float4 xs[64 * 4];
    int t = threadIdx.x;                      // output dim d (0..127)
    float w[16];
#pragma unroll
    for (int f = 0; f < 16; ++f) w[f] = Wemb[t * 16 + f];
    int n0 = blockIdx.x * 64;
    const float4* x4 = (const float4*)x;
    for (int idx = t; idx < 64 * 4; idx += 128) {
        int gi = n0 * 4 + idx;
        xs[idx] = (gi < N_ * 4) ? x4[gi] : make_float4(0.f, 0.f, 0.f, 0.f);
    }
    __syncthreads();
    int lim = min(64, N_ - n0);
    for (int j = 0; j < lim; ++j) {
        float4 x0 = xs[j * 4 + 0], x1 = xs[j * 4 + 1];
        float4 x2 = xs[j * 4 + 2], x3 = xs[j * 4 + 3];
        float acc = x0.x * w[0] + x0.y * w[1] + x0.z * w[2] + x0.w * w[3]
                  + x1.x * w[4] + x1.y * w[5] + x1.z * w[6] + x1.w * w[7]
                  + x2.x * w[8] + x2.y * w[9] + x2.z * w[10] + x2.w * w[11]
                  + x3.x * w[12] + x3.y * w[13] + x3.z * w[14] + x3.w * w[15];
        h[(size_t)(n0 + j) * 128 + t] = (_Float16)acc;
    }
}

// ---------------- MFMA GEMM: D[c][n] = sum_k W[c][k] * h[n][k] ----------
// mfma_f32_16x16x32_f16, fp32 accumulate. Per m89-verified C/D layout
// (col=lane&15=node, row=4*(lane>>4)+reg=c) each lane ends with 4
// CONSECUTIVE c values for one node -> packed 8B stores, no transpose.
// A-frag: lane reads W[c0+(l&15)][8*(l>>4)+j] (cvt fp32->f16).
// B-frag: lane reads h[nb+(l&15)][8*(l>>4)+j] (16B fp16 load).
// Block: 4 waves, 128 nodes x 128 cols; wave w covers c in {16w, 16w+64}.
// FP16OUT=1: mh = fp16(dis[n]*out); FP16OUT=0: fp32 out (dots).
template<int FP16OUT>
__global__ __launch_bounds__(256) void mfma_gemm(
    const _Float16* __restrict__ h, const float* __restrict__ W,
    void* __restrict__ outp, int ncols, const float* __restrict__ dis) {
    int t = threadIdx.x;
    int w = t >> 6;                    // wave 0..3
    int l = t & 63;
    int l15 = l & 15;
    int g = l >> 4;                    // 0..3
    int nb0 = blockIdx.x * 128;

    // A-frags: 2 c-groups x 4 K-steps, held in registers for whole kernel
    f16x8 afr[2][4];
#pragma unroll
    for (int cg = 0; cg < 2; ++cg) {
        int c = 16 * w + 64 * cg + l15;
#pragma unroll
        for (int ks = 0; ks < 4; ++ks) {
            f16x8 af = {0, 0, 0, 0, 0, 0, 0, 0};
            if (c < ncols) {
                const float* wp = &W[c * 128 + 32 * ks + 8 * g];
                float4 w0 = *(const float4*)wp;
                float4 w1 = *(const float4*)(wp + 4);
                af[0] = (_Float16)w0.x; af[1] = (_Float16)w0.y;
                af[2] = (_Float16)w0.z; af[3] = (_Float16)w0.w;
                af[4] = (_Float16)w1.x; af[5] = (_Float16)w1.y;
                af[6] = (_Float16)w1.z; af[7] = (_Float16)w1.w;
            }
            afr[cg][ks] = af;
        }
    }

    for (int nt = 0; nt < 8; ++nt) {
        int nb = nb0 + 16 * nt;
        int node = nb + l15;
        int nodeL = node < N_ ? node : 0;
        f16x8 bfr[4];
#pragma unroll
        for (int ks = 0; ks < 4; ++ks)
            bfr[ks] = *(const f16x8*)&h[(size_t)nodeL * 128 + 32 * ks + 8 * g];
        f32x4 acc0 = {0.f, 0.f, 0.f, 0.f};
        f32x4 acc1 = {0.f, 0.f, 0.f, 0.f};
#pragma unroll
        for (int ks = 0; ks < 4; ++ks) {
            acc0 = __builtin_amdgcn_mfma_f32_16x16x32_f16(afr[0][ks], bfr[ks], acc0, 0, 0, 0);
            acc1 = __builtin_amdgcn_mfma_f32_16x16x32_f16(afr[1][ks], bfr[ks], acc1, 0, 0, 0);
        }
        if (node < N_) {
            int cb = 16 * w + 4 * g;
            if (FP16OUT) {
                float s = dis[node];
                ushort* mh = (ushort*)outp;
                __half2 p01 = __float22half2_rn(make_float2(acc0[0] * s, acc0[1] * s));
                __half2 p23 = __float22half2_rn(make_float2(acc0[2] * s, acc0[3] * s));
                uint2 u0;
                u0.x = *(unsigned int*)&p01; u0.y = *(unsigned int*)&p23;
                *(uint2*)&mh[(size_t)node * 128 + cb] = u0;
                __half2 q01 = __float22half2_rn(make_float2(acc1[0] * s, acc1[1] * s));
                __half2 q23 = __float22half2_rn(make_float2(acc1[2] * s, acc1[3] * s));
                uint2 u1;
                u1.x = *(unsigned int*)&q01; u1.y = *(unsigned int*)&q23;
                *(uint2*)&mh[(size_t)node * 128 + cb + 64] = u1;
            } else {
                float* o = (float*)outp;
                *(float4*)&o[(size_t)node * 128 + cb] =
                    make_float4(acc0[0], acc0[1], acc0[2], acc0[3]);
                *(float4*)&o[(size_t)node * 128 + cb + 64] =
                    make_float4(acc1[0], acc1[1], acc1[2], acc1[3]);
            }
        }
    }
}

__device__ inline float4 h4f4(uint2 u) {
    float2 fa = __half22float2(*(__half2*)&u.x);
    float2 fb = __half22float2(*(__half2*)&u.y);
    return make_float4(fa.x, fa.y, fb.x, fb.y);
}

// ---------------- GCN aggregate: h[i] = fp16(relu(di * sum mh[s])) -------
// mh fp16 rows (256B). 32 lanes per node, 8B/lane gathers, shfl-broadcast idx.
__global__ __launch_bounds__(256) void aggregate(
    const ushort* __restrict__ mh, _Float16* __restrict__ hout,
    const int* __restrict__ rowp, const int* __restrict__ csr,
    const float* __restrict__ dis, float* __restrict__ x2out) {
    int t = threadIdx.x;
    int lane = t & 63;
    int l32 = lane & 31;
    int hbase = lane & 32;                       // 0 | 32
    int node = blockIdx.x * 8 + ((t >> 6) << 1) + (hbase >> 5);   // N_ % 8 == 0
    const uint2* m2 = (const uint2*)mh;

    float4 acc0 = h4f4(m2[(size_t)node * 32 + l32]);   // self-loop term
    float4 acc1 = make_float4(0.f, 0.f, 0.f, 0.f);
    int beg = rowp[node], end = rowp[node + 1];
    for (int base = beg; base < end; base += 32) {
        int cnt = end - base; if (cnt > 32) cnt = 32;
        int myidx = (l32 < cnt) ? csr[base + l32] : 0;
        int j = 0;
        for (; j + 8 <= cnt; j += 8) {
            int s0 = __shfl(myidx, hbase + j);
            int s1 = __shfl(myidx, hbase + j + 1);
            int s2 = __shfl(myidx, hbase + j + 2);
            int s3 = __shfl(myidx, hbase + j + 3);
            int s4 = __shfl(myidx, hbase + j + 4);
            int s5 = __shfl(myidx, hbase + j + 5);
            int s6 = __shfl(myidx, hbase + j + 6);
            int s7 = __shfl(myidx, hbase + j + 7);
            uint2 u0 = m2[(size_t)s0 * 32 + l32];
            uint2 u1 = m2[(size_t)s1 * 32 + l32];
            uint2 u2 = m2[(size_t)s2 * 32 + l32];
            uint2 u3 = m2[(size_t)s3 * 32 + l32];
            uint2 u4 = m2[(size_t)s4 * 32 + l32];
            uint2 u5 = m2[(size_t)s5 * 32 + l32];
            uint2 u6 = m2[(size_t)s6 * 32 + l32];
            uint2 u7 = m2[(size_t)s7 * 32 + l32];
            float4 v0 = h4f4(u0), v1 = h4f4(u1), v2 = h4f4(u2), v3 = h4f4(u3);
            float4 v4 = h4f4(u4), v5 = h4f4(u5), v6 = h4f4(u6), v7 = h4f4(u7);
            acc0.x += (v0.x + v1.x) + (v2.x + v3.x);
            acc0.y += (v0.y + v1.y) + (v2.y + v3.y);
            acc0.z += (v0.z + v1.z) + (v2.z + v3.z);
            acc0.w += (v0.w + v1.w) + (v2.w + v3.w);
            acc1.x += (v4.x + v5.x) + (v6.x + v7.x);
            acc1.y += (v4.y + v5.y) + (v6.y + v7.y);
            acc1.z += (v4.z + v5.z) + (v6.z + v7.z);
            acc1.w += (v4.w + v5.w) + (v6.w + v7.w);
        }
        for (; j + 4 <= cnt; j += 4) {
            int s0 = __shfl(myidx, hbase + j);
            int s1 = __shfl(myidx, hbase + j + 1);
            int s2 = __shfl(myidx, hbase + j + 2);
            int s3 = __shfl(myidx, hbase + j + 3);
            uint2 u0 = m2[(size_t)s0 * 32 + l32];
            uint2 u1 = m2[(size_t)s1 * 32 + l32];
            uint2 u2 = m2[(size_t)s2 * 32 + l32];
            uint2 u3 = m2[(size_t)s3 * 32 + l32];
            float4 v0 = h4f4(u0), v1 = h4f4(u1), v2 = h4f4(u2), v3 = h4f4(u3);
            acc0.x += (v0.x + v1.x) + (v2.x + v3.x);
            acc0.y += (v0.y + v1.y) + (v2.y + v3.y);
            acc0.z += (v0.z + v1.z) + (v2.z + v3.z);
            acc0.w += (v0.w + v1.w) + (v2.w + v3.w);
        }
        for (; j < cnt; ++j) {
            int s = __shfl(myidx, hbase + j);
            float4 v = h4f4(m2[(size_t)s * 32 + l32]);
            acc1.x += v.x; acc1.y += v.y; acc1.z += v.z; acc1.w += v.w;
        }
    }
    float di = dis[node];
    f16x4 hq;
    hq[0] = (_Float16)fmaxf(di * (acc0.x + acc1.x), 0.f);
    hq[1] = (_Float16)fmaxf(di * (acc0.y + acc1.y), 0.f);
    hq[2] = (_Float16)fmaxf(di * (acc0.z + acc1.z), 0.f);
    hq[3] = (_Float16)fmaxf(di * (acc0.w + acc1.w), 0.f);
    *(f16x4*)&hout[(size_t)node * 128 + (l32 << 2)] = hq;
    if (x2out) {   // row norm of the fp16-ROUNDED h (consistent with dots GEMM)
        float h0 = (float)hq[0], h1 = (float)hq[1];
        float h2 = (float)hq[2], h3 = (float)hq[3];
        float p = h0 * h0 + h1 * h1 + h2 * h2 + h3 * h3;
        p += __shfl_xor(p, 1);
        p += __shfl_xor(p, 2);
        p += __shfl_xor(p, 4);
        p += __shfl_xor(p, 8);
        p += __shfl_xor(p, 16);
        if (l32 == 0) x2out[node] = p;
    }
}

// ---------------- centroid norms (of the fp16-rounded centroids) ----------
__global__ void c2_kernel(const float* __restrict__ cent, float* __restrict__ c2) {
    int c = blockIdx.x;
    int t = threadIdx.x;    // 64
    float v0 = (float)(_Float16)cent[c * 128 + t];
    float v1 = (float)(_Float16)cent[c * 128 + 64 + t];
    float p = v0 * v0 + v1 * v1;
    for (int off = 32; off > 0; off >>= 1) p += __shfl_down(p, off);
    if (t == 0) c2[c] = p;
}

// ---------------- per-graph mean-pool of distances (batch is sorted) -------
__global__ __launch_bounds__(128) void pool_graph(
    const float* __restrict__ dots, const float* __restrict__ x2,
    const float* __restrict__ c2, const int* __restrict__ batch,
    float* __restrict__ pooled) {
    int g = blockIdx.x;
    int t = threadIdx.x;
    int lo = 0, hi = N_;
    while (lo < hi) { int mid = (lo + hi) >> 1; if (batch[mid] < g) lo = mid + 1; else hi = mid; }
    int s = lo;
    hi = N_;
    while (lo < hi) { int mid = (lo + hi) >> 1; if (batch[mid] < g + 1) lo = mid + 1; else hi = mid; }
    int e = lo;
    if (t >= C_) return;
    float cv = c2[t];
    float a0 = 0.f, a1 = 0.f, a2 = 0.f, a3 = 0.f;
    int n = s;
    for (; n + 4 <= e; n += 4) {
        float d0 = dots[(size_t)(n    ) * 128 + t];
        float d1 = dots[(size_t)(n + 1) * 128 + t];
        float d2 = dots[(size_t)(n + 2) * 128 + t];
        float d3 = dots[(size_t)(n + 3) * 128 + t];
        float x0 = x2[n], x1 = x2[n + 1], x2v = x2[n + 2], x3 = x2[n + 3];
        a0 += sqrtf(fmaxf(x0  + cv - 2.f * d0, 0.f) + 1e-12f);
        a1 += sqrtf(fmaxf(x1  + cv - 2.f * d1, 0.f) + 1e-12f);
        a2 += sqrtf(fmaxf(x2v + cv - 2.f * d2, 0.f) + 1e-12f);
        a3 += sqrtf(fmaxf(x3  + cv - 2.f * d3, 0.f) + 1e-12f);
    }
    for (; n < e; ++n) {
        float d = dots[(size_t)n * 128 + t];
        a0 += sqrtf(fmaxf(x2[n] + cv - 2.f * d, 0.f) + 1e-12f);
    }
    float inv = 1.0f / fmaxf((float)(e - s), 1.0f);
    pooled[g * C_ + t] = (a0 + a1 + a2 + a3) * inv;
}

// ---------------- final: out = pooled @ W_out^T + b_out ----------------
__global__ void final_out(const float* __restrict__ pooled,
                          const float* __restrict__ W_out, const float* __restrict__ b_out,
                          float* __restrict__ out) {
    int i = blockIdx.x * 256 + threadIdx.x;
    if (i >= G_ * K_) return;
    int g = i >> 1, k = i & 1;
    float acc = 0.f;
    for (int c = 0; c < C_; ++c) acc += pooled[g * C_ + c] * W_out[k * C_ + c];
    out[i] = acc + b_out[k];
}

extern "C" void kernel_launch(void* const* d_in, const int* in_sizes, int n_in,
                              void* d_out, int out_size, void* d_ws, size_t ws_size,
                              hipStream_t stream) {
    const float* x       = (const float*)d_in[0];
    const int*   eidx    = (const int*)d_in[1];    // [2][E]: src then dst
    const int*   batch   = (const int*)d_in[2];
    const float* W_embed = (const float*)d_in[3];
    const float* W_convs = (const float*)d_in[4];
    const float* cent    = (const float*)d_in[5];
    const float* W_out   = (const float*)d_in[6];
    const float* b_out   = (const float*)d_in[7];
    float* out = (float*)d_out;

    char* p = (char*)d_ws;
    _Float16* h  = (_Float16*)p; p += (size_t)N_ * D_ * 2;  // fp16 node features
    float*  dots = (float*)p;  p += (size_t)N_ * D_ * 4;    // fp32 h@cent^T
    ushort* mh   = (ushort*)p; p += (size_t)N_ * D_ * 2;    // fp16 messages
    int*   deg  = (int*)p;   p += (size_t)N_ * 4;
    float* dis  = (float*)p; p += (size_t)N_ * 4;
    int*   rowp = (int*)p;   p += (size_t)(N_ + 2) * 4;
    int*   curs = (int*)p;   p += (size_t)N_ * 4;
    int*   csr  = (int*)p;   p += (size_t)E_ * 4;
    int*   bsum = (int*)p;   p += (size_t)512 * 4;
    float* c2   = (float*)p; p += (size_t)128 * 4;
    float* x2   = (float*)p; p += (size_t)N_ * 4;
    float* pool = (float*)p; p += (size_t)G_ * C_ * 4;

    const int* esrc = eidx;
    const int* edst = eidx + E_;

    init_ws<<<(N_ + 255) / 256, 256, 0, stream>>>(deg, curs);
    count_deg<<<(E_ + 255) / 256, 256, 0, stream>>>(edst, deg);
    compute_disq<<<(N_ + 255) / 256, 256, 0, stream>>>(deg, dis);
    scan_block_sums<<<NSB, 256, 0, stream>>>(deg, bsum);
    scan_offsets<<<1, 512, 0, stream>>>(bsum, NSB);
    scan_write<<<NSB, 256, 0, stream>>>(deg, bsum, rowp);
    fill_csr_xcd<<<NR_ * NCH_, 256, 0, stream>>>(esrc, edst, rowp, curs, csr);

    // h0 = fp16(x @ W_embed^T)
    embed_kernel<<<(N_ + 63) / 64, 128, 0, stream>>>(x, W_embed, h);

    int ngb = (N_ + 127) / 128;   // 782
    for (int l = 0; l < L_; ++l) {
        mfma_gemm<1><<<ngb, 256, 0, stream>>>(h, W_convs + (size_t)l * D_ * D_,
                                              (void*)mh, 128, dis);
        aggregate<<<N_ / 8, 256, 0, stream>>>(mh, h, rowp, csr, dis,
                                              (l == L_ - 1) ? x2 : nullptr);
    }

    // dots = h @ centroids^T (cols 100..127 zeroed via A-frag guard)
    mfma_gemm<0><<<ngb, 256, 0, stream>>>(h, cent, (void*)dots, 100, nullptr);
    c2_kernel<<<C_, 64, 0, stream>>>(cent, c2);
    pool_graph<<<G_, 128, 0, stream>>>(dots, x2, c2, batch, pool);
    final_out<<<(G_ * K_ + 255) / 256, 256, 0, stream>>>(pool, W_out, b_out, out);
}